// Round 9
// baseline (426.813 us; speedup 1.0000x reference)
//
#include <hip/hip_runtime.h>

// Problem constants (inputs: (32,64,32,32) fp32; embed: (64,1024) fp32)
#define N_PIX  32768   // B*H*W
#define C_DIM  64
#define K_EMB  1024
#define HW     1024    // H*W
#define P_TILE 8       // pixels per block
#define NBLK   (N_PIX / P_TILE)   // 4096

// d_out layout (float32, concatenated in return order):
//   quantized_out (B,C,H,W) | loss | encoding_indices | perplexity
#define OUT_Q_OFF    0
#define OUT_LOSS_OFF 2097152
#define OUT_IDX_OFF  2097153
#define OUT_PERP_OFF 2129921

// ws layout: counts[1024] u32 @0 | lossAcc f32 @4096 | done u32 @4100
//            (memset 4104 B, the only extra enqueued op)

__device__ __forceinline__ unsigned long long pack_score(float d, int k) {
    unsigned int u = __float_as_uint(d);
    u = (u & 0x80000000u) ? ~u : (u | 0x80000000u);  // monotone map, negative-safe
    return ((unsigned long long)u << 32) | (unsigned int)k;
}

// Round-9: r8's proven hot loop (84.5us) kept verbatim; epilogue changed to
//   - global atomic histogram (8 adds/block, overlapped with other blocks' compute)
//   - 1 loss atomicAdd/block
//   - last-done-block finalize (threadfence release/acquire + done counter):
//     computes perplexity+loss scalars inline, deleting the k_fin launch whose
//     single-block histogram cost ~25-30us serialized after the grid drained.
__global__ __launch_bounds__(128, 4) void k_main(
    const float* __restrict__ inp, const float* __restrict__ embed,
    unsigned int* __restrict__ counts, float* __restrict__ lossAcc,
    unsigned int* __restrict__ done, float* __restrict__ out_q,
    float* __restrict__ out_idx, float* __restrict__ out_loss,
    float* __restrict__ out_perp) {
    __shared__ float x_lds[C_DIM * P_TILE];           // 2 KB
    __shared__ unsigned long long red[2][P_TILE];
    __shared__ int ksel[P_TILE];
    __shared__ float lred[2];
    __shared__ unsigned int isLast;

    const int tid = threadIdx.x;                      // 0..127
    const int n0  = blockIdx.x * P_TILE;
    const int b   = n0 >> 10;
    const int hw0 = n0 & 1023;
    const float* __restrict__ xu = inp + b * (C_DIM * HW) + hw0;

    // stage x tile: 128 threads -> (c = tid>>1, one float4 half-row)
    {
        const int c  = tid >> 1;
        const int p4 = (tid & 1) * 4;
        *reinterpret_cast<float4*>(&x_lds[c * P_TILE + p4]) =
            *reinterpret_cast<const float4*>(xu + c * HW + p4);
    }
    __syncthreads();

    const int kL = tid * 4;            // low-half quad
    const int kH = 512 + tid * 4;      // high-half quad
    const float4* __restrict__ ebL = reinterpret_cast<const float4*>(embed) + tid;
    const float4* __restrict__ ebH = ebL + 128;   // +512 floats; row stride 256 float4

    float4 aL0={0,0,0,0},aL1={0,0,0,0},aL2={0,0,0,0},aL3={0,0,0,0};
    float4 aL4={0,0,0,0},aL5={0,0,0,0},aL6={0,0,0,0},aL7={0,0,0,0};
    float4 aH0={0,0,0,0},aH1={0,0,0,0},aH2={0,0,0,0},aH3={0,0,0,0};
    float4 aH4={0,0,0,0},aH5={0,0,0,0},aH6={0,0,0,0},aH7={0,0,0,0};
    float4 eeL={0,0,0,0}, eeH={0,0,0,0};

#define FMA8(i, xv, EL, EH) \
    aL##i.x = fmaf((xv), EL.x, aL##i.x); aL##i.y = fmaf((xv), EL.y, aL##i.y); \
    aL##i.z = fmaf((xv), EL.z, aL##i.z); aL##i.w = fmaf((xv), EL.w, aL##i.w); \
    aH##i.x = fmaf((xv), EH.x, aH##i.x); aH##i.y = fmaf((xv), EH.y, aH##i.y); \
    aH##i.z = fmaf((xv), EH.z, aH##i.z); aH##i.w = fmaf((xv), EH.w, aH##i.w);

#define BODY(EL, EH, A, B) { \
    eeL.x = fmaf(EL.x, EL.x, eeL.x); eeL.y = fmaf(EL.y, EL.y, eeL.y); \
    eeL.z = fmaf(EL.z, EL.z, eeL.z); eeL.w = fmaf(EL.w, EL.w, eeL.w); \
    eeH.x = fmaf(EH.x, EH.x, eeH.x); eeH.y = fmaf(EH.y, EH.y, eeH.y); \
    eeH.z = fmaf(EH.z, EH.z, eeH.z); eeH.w = fmaf(EH.w, EH.w, eeH.w); \
    FMA8(0, A.x, EL, EH) FMA8(1, A.y, EL, EH) \
    FMA8(2, A.z, EL, EH) FMA8(3, A.w, EL, EH) \
    FMA8(4, B.x, EL, EH) FMA8(5, B.y, EL, EH) \
    FMA8(6, B.z, EL, EH) FMA8(7, B.w, EL, EH) }

    float4 EL0 = ebL[0],   EH0 = ebH[0];
    float4 EL1 = ebL[256], EH1 = ebH[256];
    float4 XA = *reinterpret_cast<const float4*>(&x_lds[0]);
    float4 XB = *reinterpret_cast<const float4*>(&x_lds[4]);

#pragma unroll 1
    for (int c = 0; c < C_DIM; c += 2) {
        const int c2 = (c + 2) & 63, c3 = (c + 3) & 63;   // tail-safe wrap
        float4 NL0 = ebL[c2 * 256], NH0 = ebH[c2 * 256];
        float4 NL1 = ebL[c3 * 256], NH1 = ebH[c3 * 256];
        const float4 YA = *reinterpret_cast<const float4*>(&x_lds[(c + 1) * P_TILE + 0]);
        const float4 YB = *reinterpret_cast<const float4*>(&x_lds[(c + 1) * P_TILE + 4]);
        BODY(EL0, EH0, XA, XB)
        XA = *reinterpret_cast<const float4*>(&x_lds[c2 * P_TILE + 0]);
        XB = *reinterpret_cast<const float4*>(&x_lds[c2 * P_TILE + 4]);
        BODY(EL1, EH1, YA, YB)
        EL0 = NL0; EH0 = NH0; EL1 = NL1; EH1 = NH1;
    }
#undef BODY
#undef FMA8

    // per-pixel packed argmin: 8 candidate k's per thread, then 2-wave reduce
    const int wv = tid >> 6, ln = tid & 63;
#define RED_P(i) { \
        const float s0 = fmaf(-2.f, aL##i.x, eeL.x); \
        const float s1 = fmaf(-2.f, aL##i.y, eeL.y); \
        const float s2 = fmaf(-2.f, aL##i.z, eeL.z); \
        const float s3 = fmaf(-2.f, aL##i.w, eeL.w); \
        const float s4 = fmaf(-2.f, aH##i.x, eeH.x); \
        const float s5 = fmaf(-2.f, aH##i.y, eeH.y); \
        const float s6 = fmaf(-2.f, aH##i.z, eeH.z); \
        const float s7 = fmaf(-2.f, aH##i.w, eeH.w); \
        unsigned long long m = pack_score(s0, kL), t; \
        t = pack_score(s1, kL + 1); if (t < m) m = t; \
        t = pack_score(s2, kL + 2); if (t < m) m = t; \
        t = pack_score(s3, kL + 3); if (t < m) m = t; \
        t = pack_score(s4, kH);     if (t < m) m = t; \
        t = pack_score(s5, kH + 1); if (t < m) m = t; \
        t = pack_score(s6, kH + 2); if (t < m) m = t; \
        t = pack_score(s7, kH + 3); if (t < m) m = t; \
        for (int off = 32; off > 0; off >>= 1) { \
            unsigned long long o = __shfl_down(m, off, 64); \
            if (o < m) m = o; \
        } \
        if (ln == 0) red[wv][i] = m; }
    RED_P(0) RED_P(1) RED_P(2) RED_P(3)
    RED_P(4) RED_P(5) RED_P(6) RED_P(7)
#undef RED_P

    __syncthreads();
    if (tid < P_TILE) {
        unsigned long long m = red[0][tid];
        if (red[1][tid] < m) m = red[1][tid];
        const int k = (int)(unsigned int)(m & 0xFFFFFFFFull);
        ksel[tid] = k;
        out_idx[n0 + tid] = (float)k;
        atomicAdd(counts + k, 1u);   // overlapped global histogram
    }
    __syncthreads();

    // fused quantize + loss: 128 threads -> (c = tid>>1, 4 pixels); x from LDS
    {
        const int c  = tid >> 1;
        const int pb = (tid & 1) * 4;
        float ls = 0.f;
        float4 qv;
        float* qvp = &qv.x;
#pragma unroll
        for (int j = 0; j < 4; ++j) {
            const int k = ksel[pb + j];
            const float q  = embed[c * K_EMB + k];  // gather, L2-resident table
            const float xv = x_lds[c * P_TILE + pb + j];
            const float d  = q - xv;
            ls = fmaf(d, d, ls);
            qvp[j] = q;
        }
        *reinterpret_cast<float4*>(out_q + b * (C_DIM * HW) + c * HW + hw0 + pb) = qv;
        for (int off = 32; off > 0; off >>= 1) ls += __shfl_down(ls, off, 64);
        if (ln == 0) lred[wv] = ls;
    }
    __syncthreads();
    if (tid == 0) atomicAdd(lossAcc, lred[0] + lred[1]);

    // ---- last-done-block finalize (release/acquire via done counter) ----
    __threadfence();                                  // release our atomics
    if (tid == 0) isLast = (atomicAdd(done, 1u) == (unsigned)(NBLK - 1));
    __syncthreads();
    if (isLast) {
        __threadfence();                              // acquire all blocks' atomics
        float t = 0.f;
#pragma unroll
        for (int j = 0; j < 8; ++j) {
            const float p = (float)counts[tid * 8 + j] * (1.0f / (float)N_PIX);
            t = fmaf(p, logf(p + 1e-10f), t);         // p==0 -> exactly 0
        }
        for (int off = 32; off > 0; off >>= 1) t += __shfl_down(t, off, 64);
        if (ln == 0) lred[wv] = t;                    // reuse lred
        __syncthreads();
        if (tid == 0) {
            *out_perp = expf(-(lred[0] + lred[1]));
            *out_loss = 0.25f * (*lossAcc) * (1.0f / (float)(N_PIX * C_DIM));
        }
    }
}

extern "C" void kernel_launch(void* const* d_in, const int* in_sizes, int n_in,
                              void* d_out, int out_size, void* d_ws, size_t ws_size,
                              hipStream_t stream) {
    const float* inp   = (const float*)d_in[0];
    const float* embed = (const float*)d_in[1];
    float* out = (float*)d_out;

    char* ws = (char*)d_ws;
    unsigned int* counts  = (unsigned int*)(ws + 0);
    float*        lossAcc = (float*)(ws + 4096);
    unsigned int* done    = (unsigned int*)(ws + 4100);

    hipMemsetAsync(ws, 0, 4104, stream);  // counts + lossAcc + done

    k_main<<<dim3(NBLK), dim3(128), 0, stream>>>(
        inp, embed, counts, lossAcc, done,
        out + OUT_Q_OFF, out + OUT_IDX_OFF, out + OUT_LOSS_OFF, out + OUT_PERP_OFF);
}

// Round 10
// 167.040 us; speedup vs baseline: 2.5552x; 2.5552x over previous
//
#include <hip/hip_runtime.h>

// Problem constants (inputs: (32,64,32,32) fp32; embed: (64,1024) fp32)
#define N_PIX  32768   // B*H*W
#define C_DIM  64
#define K_EMB  1024
#define HW     1024    // H*W
#define P_TILE 8       // pixels per block
#define NBLK   (N_PIX / P_TILE)   // 4096

// d_out layout (float32, concatenated in return order):
//   quantized_out (B,C,H,W) | loss | encoding_indices | perplexity
#define OUT_Q_OFF    0
#define OUT_LOSS_OFF 2097152
#define OUT_IDX_OFF  2097153
#define OUT_PERP_OFF 2129921

// ws layout: counts[1024] u32 @0 | lossAcc f32 @4096 | e2[1024] f32 @8192
//   memset zeroes [0,4104); e2 written by k_e2 before k_main reads it.
// NOTE (r9 lesson): NO __threadfence() in k_main — device-scope fences on
// gfx950 trigger per-XCD L2 writeback/invalidate; 4096 blocks fencing took
// k_main 84.5 -> 378us. Cross-block reductions live in k_scalar instead
// (kernel boundary = the cheap fence).

__device__ __forceinline__ unsigned long long pack_score(float d, int k) {
    unsigned int u = __float_as_uint(d);
    u = (u & 0x80000000u) ? ~u : (u | 0x80000000u);  // monotone map, negative-safe
    return ((unsigned long long)u << 32) | (unsigned int)k;
}

__global__ void k_e2(const float* __restrict__ embed, float* __restrict__ e2) {
    int k = blockIdx.x * blockDim.x + threadIdx.x;  // 0..1023
    float s = 0.f;
#pragma unroll
    for (int c = 0; c < C_DIM; ++c) {
        float v = embed[c * K_EMB + k];
        s = fmaf(v, v, s);
    }
    e2[k] = s;
}

// Round-10 k_main = r8's proven hot loop (84.5us) minus the fused ee-FMAs
// (e2 precomputed by k_e2, loaded post-loop as 2 coalesced float4s = -11%
// issue) and with `#pragma unroll 2` so the allocator renames N->E across
// iterations instead of emitting 16 v_movs per body (-~10% issue).
// Histogram/loss: r7-proven global atomics (8+1 per block, overlapped).
__global__ __launch_bounds__(128, 4) void k_main(
    const float* __restrict__ inp, const float* __restrict__ embed,
    const float* __restrict__ e2, unsigned int* __restrict__ counts,
    float* __restrict__ lossAcc, float* __restrict__ out_q,
    float* __restrict__ out_idx) {
    __shared__ float x_lds[C_DIM * P_TILE];           // 2 KB
    __shared__ unsigned long long red[2][P_TILE];
    __shared__ int ksel[P_TILE];
    __shared__ float lred[2];

    const int tid = threadIdx.x;                      // 0..127
    const int n0  = blockIdx.x * P_TILE;
    const int b   = n0 >> 10;
    const int hw0 = n0 & 1023;
    const float* __restrict__ xu = inp + b * (C_DIM * HW) + hw0;

    // stage x tile: 128 threads -> (c = tid>>1, one float4 half-row)
    {
        const int c  = tid >> 1;
        const int p4 = (tid & 1) * 4;
        *reinterpret_cast<float4*>(&x_lds[c * P_TILE + p4]) =
            *reinterpret_cast<const float4*>(xu + c * HW + p4);
    }
    __syncthreads();

    const int kL = tid * 4;            // low-half quad
    const int kH = 512 + tid * 4;      // high-half quad
    const float4* __restrict__ ebL = reinterpret_cast<const float4*>(embed) + tid;
    const float4* __restrict__ ebH = ebL + 128;   // +512 floats; row stride 256 float4

    float4 aL0={0,0,0,0},aL1={0,0,0,0},aL2={0,0,0,0},aL3={0,0,0,0};
    float4 aL4={0,0,0,0},aL5={0,0,0,0},aL6={0,0,0,0},aL7={0,0,0,0};
    float4 aH0={0,0,0,0},aH1={0,0,0,0},aH2={0,0,0,0},aH3={0,0,0,0};
    float4 aH4={0,0,0,0},aH5={0,0,0,0},aH6={0,0,0,0},aH7={0,0,0,0};

#define FMA8(i, xv, EL, EH) \
    aL##i.x = fmaf((xv), EL.x, aL##i.x); aL##i.y = fmaf((xv), EL.y, aL##i.y); \
    aL##i.z = fmaf((xv), EL.z, aL##i.z); aL##i.w = fmaf((xv), EL.w, aL##i.w); \
    aH##i.x = fmaf((xv), EH.x, aH##i.x); aH##i.y = fmaf((xv), EH.y, aH##i.y); \
    aH##i.z = fmaf((xv), EH.z, aH##i.z); aH##i.w = fmaf((xv), EH.w, aH##i.w);

#define BODY(EL, EH, A, B) { \
    FMA8(0, A.x, EL, EH) FMA8(1, A.y, EL, EH) \
    FMA8(2, A.z, EL, EH) FMA8(3, A.w, EL, EH) \
    FMA8(4, B.x, EL, EH) FMA8(5, B.y, EL, EH) \
    FMA8(6, B.z, EL, EH) FMA8(7, B.w, EL, EH) }

    float4 EL0 = ebL[0],   EH0 = ebH[0];
    float4 EL1 = ebL[256], EH1 = ebH[256];
    float4 XA = *reinterpret_cast<const float4*>(&x_lds[0]);
    float4 XB = *reinterpret_cast<const float4*>(&x_lds[4]);

#pragma unroll 2
    for (int c = 0; c < C_DIM; c += 2) {
        const int c2 = (c + 2) & 63, c3 = (c + 3) & 63;   // tail-safe wrap
        float4 NL0 = ebL[c2 * 256], NH0 = ebH[c2 * 256];
        float4 NL1 = ebL[c3 * 256], NH1 = ebH[c3 * 256];
        const float4 YA = *reinterpret_cast<const float4*>(&x_lds[(c + 1) * P_TILE + 0]);
        const float4 YB = *reinterpret_cast<const float4*>(&x_lds[(c + 1) * P_TILE + 4]);
        BODY(EL0, EH0, XA, XB)
        XA = *reinterpret_cast<const float4*>(&x_lds[c2 * P_TILE + 0]);
        XB = *reinterpret_cast<const float4*>(&x_lds[c2 * P_TILE + 4]);
        BODY(EL1, EH1, YA, YB)
        EL0 = NL0; EH0 = NH0; EL1 = NL1; EH1 = NH1;
    }
#undef BODY
#undef FMA8

    // load precomputed ||e||^2 for this thread's 8 codes (coalesced float4)
    const float4 eeL = reinterpret_cast<const float4*>(e2)[tid];
    const float4 eeH = reinterpret_cast<const float4*>(e2)[tid + 128];

    // per-pixel packed argmin: 8 candidate k's per thread, then 2-wave reduce
    const int wv = tid >> 6, ln = tid & 63;
#define RED_P(i) { \
        const float s0 = fmaf(-2.f, aL##i.x, eeL.x); \
        const float s1 = fmaf(-2.f, aL##i.y, eeL.y); \
        const float s2 = fmaf(-2.f, aL##i.z, eeL.z); \
        const float s3 = fmaf(-2.f, aL##i.w, eeL.w); \
        const float s4 = fmaf(-2.f, aH##i.x, eeH.x); \
        const float s5 = fmaf(-2.f, aH##i.y, eeH.y); \
        const float s6 = fmaf(-2.f, aH##i.z, eeH.z); \
        const float s7 = fmaf(-2.f, aH##i.w, eeH.w); \
        unsigned long long m = pack_score(s0, kL), t; \
        t = pack_score(s1, kL + 1); if (t < m) m = t; \
        t = pack_score(s2, kL + 2); if (t < m) m = t; \
        t = pack_score(s3, kL + 3); if (t < m) m = t; \
        t = pack_score(s4, kH);     if (t < m) m = t; \
        t = pack_score(s5, kH + 1); if (t < m) m = t; \
        t = pack_score(s6, kH + 2); if (t < m) m = t; \
        t = pack_score(s7, kH + 3); if (t < m) m = t; \
        for (int off = 32; off > 0; off >>= 1) { \
            unsigned long long o = __shfl_down(m, off, 64); \
            if (o < m) m = o; \
        } \
        if (ln == 0) red[wv][i] = m; }
    RED_P(0) RED_P(1) RED_P(2) RED_P(3)
    RED_P(4) RED_P(5) RED_P(6) RED_P(7)
#undef RED_P

    __syncthreads();
    if (tid < P_TILE) {
        unsigned long long m = red[0][tid];
        if (red[1][tid] < m) m = red[1][tid];
        const int k = (int)(unsigned int)(m & 0xFFFFFFFFull);
        ksel[tid] = k;
        out_idx[n0 + tid] = (float)k;
        atomicAdd(counts + k, 1u);   // overlapped global histogram (r7-proven)
    }
    __syncthreads();

    // fused quantize + loss: 128 threads -> (c = tid>>1, 4 pixels); x from LDS
    {
        const int c  = tid >> 1;
        const int pb = (tid & 1) * 4;
        float ls = 0.f;
        float4 qv;
        float* qvp = &qv.x;
#pragma unroll
        for (int j = 0; j < 4; ++j) {
            const int k = ksel[pb + j];
            const float q  = embed[c * K_EMB + k];  // gather, L2-resident table
            const float xv = x_lds[c * P_TILE + pb + j];
            const float d  = q - xv;
            ls = fmaf(d, d, ls);
            qvp[j] = q;
        }
        *reinterpret_cast<float4*>(out_q + b * (C_DIM * HW) + c * HW + hw0 + pb) = qv;
        for (int off = 32; off > 0; off >>= 1) ls += __shfl_down(ls, off, 64);
        if (ln == 0) lred[wv] = ls;
    }
    __syncthreads();
    if (tid == 0) atomicAdd(lossAcc, lred[0] + lred[1]);  // 1 atomic per block
}

__global__ __launch_bounds__(1024) void k_scalar(
    const unsigned int* __restrict__ counts, const float* __restrict__ lossAcc,
    float* __restrict__ out_loss, float* __restrict__ out_perp) {
    __shared__ float red[16];
    const int tid = threadIdx.x;  // 0..1023
    float p = (float)counts[tid] * (1.0f / (float)N_PIX);
    float t = p * logf(p + 1e-10f);   // p==0 -> exactly 0, matches reference
    for (int off = 32; off > 0; off >>= 1) t += __shfl_down(t, off, 64);
    if ((tid & 63) == 0) red[tid >> 6] = t;
    __syncthreads();
    if (tid == 0) {
        float s = 0.f;
#pragma unroll
        for (int i = 0; i < 16; ++i) s += red[i];
        *out_perp = expf(-s);
        *out_loss = 0.25f * (*lossAcc) * (1.0f / (float)(N_PIX * C_DIM));
    }
}

extern "C" void kernel_launch(void* const* d_in, const int* in_sizes, int n_in,
                              void* d_out, int out_size, void* d_ws, size_t ws_size,
                              hipStream_t stream) {
    const float* inp   = (const float*)d_in[0];
    const float* embed = (const float*)d_in[1];
    float* out = (float*)d_out;

    char* ws = (char*)d_ws;
    unsigned int* counts  = (unsigned int*)(ws + 0);
    float*        lossAcc = (float*)(ws + 4096);
    float*        e2      = (float*)(ws + 8192);

    hipMemsetAsync(ws, 0, 4104, stream);  // counts + lossAcc

    k_e2<<<dim3(K_EMB / 256), dim3(256), 0, stream>>>(embed, e2);
    k_main<<<dim3(NBLK), dim3(128), 0, stream>>>(
        inp, embed, e2, counts, lossAcc, out + OUT_Q_OFF, out + OUT_IDX_OFF);
    k_scalar<<<dim3(1), dim3(1024), 0, stream>>>(counts, lossAcc,
        out + OUT_LOSS_OFF, out + OUT_PERP_OFF);
}

// Round 11
// 150.178 us; speedup vs baseline: 2.8420x; 1.1123x over previous
//
#include <hip/hip_runtime.h>

// Problem constants (inputs: (32,64,32,32) fp32; embed: (64,1024) fp32)
#define N_PIX  32768   // B*H*W
#define C_DIM  64
#define K_EMB  1024
#define HW     1024    // H*W
#define P_TILE 8       // pixels per block
#define NBLK   (N_PIX / P_TILE)   // 4096

// d_out layout (float32, concatenated in return order):
//   quantized_out (B,C,H,W) | loss | encoding_indices | perplexity
#define OUT_Q_OFF    0
#define OUT_LOSS_OFF 2097152
#define OUT_IDX_OFF  2097153
#define OUT_PERP_OFF 2129921

// ws layout: counts[1024] u32 @0 | lossAcc f32 @4096   (memset 4104 B)
// Lessons encoded here:
//  - r9: NO __threadfence in the grid kernel (per-XCD L2 writeback storm).
//  - r10: NO unroll>1 on the c-loop (live-range doubling -> scratch spill,
//    WRITE_SIZE 16->27 MB). r8's unroll-1 + 2-deep rotation is the proven shape.
//  - r1/r5: accumulators must be NAMED float4s, no address-taking.

__device__ __forceinline__ unsigned long long pack_score(float d, int k) {
    unsigned int u = __float_as_uint(d);
    u = (u & 0x80000000u) ? ~u : (u | 0x80000000u);  // monotone map, negative-safe
    return ((unsigned long long)u << 32) | (unsigned int)k;
}

// r8's proven hot loop (84.5us) verbatim; epilogue = r7-proven global atomics
// (8 hist + 1 loss per block, overlapped with other blocks' compute).
__global__ __launch_bounds__(128, 4) void k_main(
    const float* __restrict__ inp, const float* __restrict__ embed,
    unsigned int* __restrict__ counts, float* __restrict__ lossAcc,
    float* __restrict__ out_q, float* __restrict__ out_idx) {
    __shared__ float x_lds[C_DIM * P_TILE];           // 2 KB
    __shared__ unsigned long long red[2][P_TILE];
    __shared__ int ksel[P_TILE];
    __shared__ float lred[2];

    const int tid = threadIdx.x;                      // 0..127
    const int n0  = blockIdx.x * P_TILE;
    const int b   = n0 >> 10;
    const int hw0 = n0 & 1023;
    const float* __restrict__ xu = inp + b * (C_DIM * HW) + hw0;

    // stage x tile: 128 threads -> (c = tid>>1, one float4 half-row)
    {
        const int c  = tid >> 1;
        const int p4 = (tid & 1) * 4;
        *reinterpret_cast<float4*>(&x_lds[c * P_TILE + p4]) =
            *reinterpret_cast<const float4*>(xu + c * HW + p4);
    }
    __syncthreads();

    const int kL = tid * 4;            // low-half quad
    const int kH = 512 + tid * 4;      // high-half quad
    const float4* __restrict__ ebL = reinterpret_cast<const float4*>(embed) + tid;
    const float4* __restrict__ ebH = ebL + 128;   // +512 floats; row stride 256 float4

    float4 aL0={0,0,0,0},aL1={0,0,0,0},aL2={0,0,0,0},aL3={0,0,0,0};
    float4 aL4={0,0,0,0},aL5={0,0,0,0},aL6={0,0,0,0},aL7={0,0,0,0};
    float4 aH0={0,0,0,0},aH1={0,0,0,0},aH2={0,0,0,0},aH3={0,0,0,0};
    float4 aH4={0,0,0,0},aH5={0,0,0,0},aH6={0,0,0,0},aH7={0,0,0,0};
    float4 eeL={0,0,0,0}, eeH={0,0,0,0};

#define FMA8(i, xv, EL, EH) \
    aL##i.x = fmaf((xv), EL.x, aL##i.x); aL##i.y = fmaf((xv), EL.y, aL##i.y); \
    aL##i.z = fmaf((xv), EL.z, aL##i.z); aL##i.w = fmaf((xv), EL.w, aL##i.w); \
    aH##i.x = fmaf((xv), EH.x, aH##i.x); aH##i.y = fmaf((xv), EH.y, aH##i.y); \
    aH##i.z = fmaf((xv), EH.z, aH##i.z); aH##i.w = fmaf((xv), EH.w, aH##i.w);

#define BODY(EL, EH, A, B) { \
    eeL.x = fmaf(EL.x, EL.x, eeL.x); eeL.y = fmaf(EL.y, EL.y, eeL.y); \
    eeL.z = fmaf(EL.z, EL.z, eeL.z); eeL.w = fmaf(EL.w, EL.w, eeL.w); \
    eeH.x = fmaf(EH.x, EH.x, eeH.x); eeH.y = fmaf(EH.y, EH.y, eeH.y); \
    eeH.z = fmaf(EH.z, EH.z, eeH.z); eeH.w = fmaf(EH.w, EH.w, eeH.w); \
    FMA8(0, A.x, EL, EH) FMA8(1, A.y, EL, EH) \
    FMA8(2, A.z, EL, EH) FMA8(3, A.w, EL, EH) \
    FMA8(4, B.x, EL, EH) FMA8(5, B.y, EL, EH) \
    FMA8(6, B.z, EL, EH) FMA8(7, B.w, EL, EH) }

    float4 EL0 = ebL[0],   EH0 = ebH[0];
    float4 EL1 = ebL[256], EH1 = ebH[256];
    float4 XA = *reinterpret_cast<const float4*>(&x_lds[0]);
    float4 XB = *reinterpret_cast<const float4*>(&x_lds[4]);

#pragma unroll 1
    for (int c = 0; c < C_DIM; c += 2) {
        const int c2 = (c + 2) & 63, c3 = (c + 3) & 63;   // tail-safe wrap
        float4 NL0 = ebL[c2 * 256], NH0 = ebH[c2 * 256];
        float4 NL1 = ebL[c3 * 256], NH1 = ebH[c3 * 256];
        const float4 YA = *reinterpret_cast<const float4*>(&x_lds[(c + 1) * P_TILE + 0]);
        const float4 YB = *reinterpret_cast<const float4*>(&x_lds[(c + 1) * P_TILE + 4]);
        BODY(EL0, EH0, XA, XB)
        XA = *reinterpret_cast<const float4*>(&x_lds[c2 * P_TILE + 0]);
        XB = *reinterpret_cast<const float4*>(&x_lds[c2 * P_TILE + 4]);
        BODY(EL1, EH1, YA, YB)
        EL0 = NL0; EH0 = NH0; EL1 = NL1; EH1 = NH1;
    }
#undef BODY
#undef FMA8

    // per-pixel packed argmin: 8 candidate k's per thread, then 2-wave reduce
    const int wv = tid >> 6, ln = tid & 63;
#define RED_P(i) { \
        const float s0 = fmaf(-2.f, aL##i.x, eeL.x); \
        const float s1 = fmaf(-2.f, aL##i.y, eeL.y); \
        const float s2 = fmaf(-2.f, aL##i.z, eeL.z); \
        const float s3 = fmaf(-2.f, aL##i.w, eeL.w); \
        const float s4 = fmaf(-2.f, aH##i.x, eeH.x); \
        const float s5 = fmaf(-2.f, aH##i.y, eeH.y); \
        const float s6 = fmaf(-2.f, aH##i.z, eeH.z); \
        const float s7 = fmaf(-2.f, aH##i.w, eeH.w); \
        unsigned long long m = pack_score(s0, kL), t; \
        t = pack_score(s1, kL + 1); if (t < m) m = t; \
        t = pack_score(s2, kL + 2); if (t < m) m = t; \
        t = pack_score(s3, kL + 3); if (t < m) m = t; \
        t = pack_score(s4, kH);     if (t < m) m = t; \
        t = pack_score(s5, kH + 1); if (t < m) m = t; \
        t = pack_score(s6, kH + 2); if (t < m) m = t; \
        t = pack_score(s7, kH + 3); if (t < m) m = t; \
        for (int off = 32; off > 0; off >>= 1) { \
            unsigned long long o = __shfl_down(m, off, 64); \
            if (o < m) m = o; \
        } \
        if (ln == 0) red[wv][i] = m; }
    RED_P(0) RED_P(1) RED_P(2) RED_P(3)
    RED_P(4) RED_P(5) RED_P(6) RED_P(7)
#undef RED_P

    __syncthreads();
    if (tid < P_TILE) {
        unsigned long long m = red[0][tid];
        if (red[1][tid] < m) m = red[1][tid];
        const int k = (int)(unsigned int)(m & 0xFFFFFFFFull);
        ksel[tid] = k;
        out_idx[n0 + tid] = (float)k;
        atomicAdd(counts + k, 1u);   // overlapped global histogram (r7-proven)
    }
    __syncthreads();

    // fused quantize + loss: 128 threads -> (c = tid>>1, 4 pixels); x from LDS
    {
        const int c  = tid >> 1;
        const int pb = (tid & 1) * 4;
        float ls = 0.f;
        float4 qv;
        float* qvp = &qv.x;
#pragma unroll
        for (int j = 0; j < 4; ++j) {
            const int k = ksel[pb + j];
            const float q  = embed[c * K_EMB + k];  // gather, L2-resident table
            const float xv = x_lds[c * P_TILE + pb + j];
            const float d  = q - xv;
            ls = fmaf(d, d, ls);
            qvp[j] = q;
        }
        *reinterpret_cast<float4*>(out_q + b * (C_DIM * HW) + c * HW + hw0 + pb) = qv;
        for (int off = 32; off > 0; off >>= 1) ls += __shfl_down(ls, off, 64);
        if (ln == 0) lred[wv] = ls;
    }
    __syncthreads();
    if (tid == 0) atomicAdd(lossAcc, lred[0] + lred[1]);  // 1 atomic per block
}

__global__ __launch_bounds__(1024) void k_scalar(
    const unsigned int* __restrict__ counts, const float* __restrict__ lossAcc,
    float* __restrict__ out_loss, float* __restrict__ out_perp) {
    __shared__ float red[16];
    const int tid = threadIdx.x;  // 0..1023
    float p = (float)counts[tid] * (1.0f / (float)N_PIX);
    float t = p * logf(p + 1e-10f);   // p==0 -> exactly 0, matches reference
    for (int off = 32; off > 0; off >>= 1) t += __shfl_down(t, off, 64);
    if ((tid & 63) == 0) red[tid >> 6] = t;
    __syncthreads();
    if (tid == 0) {
        float s = 0.f;
#pragma unroll
        for (int i = 0; i < 16; ++i) s += red[i];
        *out_perp = expf(-s);
        *out_loss = 0.25f * (*lossAcc) * (1.0f / (float)(N_PIX * C_DIM));
    }
}

extern "C" void kernel_launch(void* const* d_in, const int* in_sizes, int n_in,
                              void* d_out, int out_size, void* d_ws, size_t ws_size,
                              hipStream_t stream) {
    const float* inp   = (const float*)d_in[0];
    const float* embed = (const float*)d_in[1];
    float* out = (float*)d_out;

    char* ws = (char*)d_ws;
    unsigned int* counts  = (unsigned int*)(ws + 0);
    float*        lossAcc = (float*)(ws + 4096);

    hipMemsetAsync(ws, 0, 4104, stream);  // counts + lossAcc

    k_main<<<dim3(NBLK), dim3(128), 0, stream>>>(
        inp, embed, counts, lossAcc, out + OUT_Q_OFF, out + OUT_IDX_OFF);
    k_scalar<<<dim3(1), dim3(1024), 0, stream>>>(counts, lossAcc,
        out + OUT_LOSS_OFF, out + OUT_PERP_OFF);
}